// Round 9
// baseline (332.599 us; speedup 1.0000x reference)
//
#include <hip/hip_runtime.h>
#include <math.h>

typedef float f32x4 __attribute__((ext_vector_type(4)));

__device__ __forceinline__ float dot4v(f32x4 a, f32x4 b){
    return a.x*b.x + a.y*b.y + a.z*b.z + a.w*b.w;
}
__device__ __forceinline__ float dot4(float4 a, float4 b){
    return a.x*b.x + a.y*b.y + a.z*b.z + a.w*b.w;
}

// Reduce four per-lane values across the 64-lane wave simultaneously.
// Result: lanes with (lane&3)==j hold sum of aj. 7 shuffles total.
__device__ __forceinline__ float reduce4(float a0, float a1, float a2, float a3, int lane){
    int b0 = lane & 1, b1 = lane & 2;
    float r  = b0 ? a1 : a0;
    float rt = b0 ? a0 : a1;
    r += __shfl_xor(rt, 1);
    float s  = b0 ? a3 : a2;
    float st = b0 ? a2 : a3;
    s += __shfl_xor(st, 1);
    float u  = b1 ? s : r;
    float ut = b1 ? r : s;
    u += __shfl_xor(ut, 2);
    u += __shfl_xor(u, 4);
    u += __shfl_xor(u, 8);
    u += __shfl_xor(u, 16);
    u += __shfl_xor(u, 32);
    return u;   // lane&3 selects which sum
}

// ---------------------------------------------------------------------------
// Grid barrier for 512 co-resident blocks. Master(bid0): 256 threads poll 2
// flags each (parallel), then release. Workers: store flag, poll release.
// AGENT-scope atomics (device-coherent across XCDs) + __threadfence for
// data visibility. Bailout counters prevent hangs on logic error.
// ---------------------------------------------------------------------------
#define NBLK 512
__device__ __forceinline__ void gbar(unsigned* flags, unsigned* rel, unsigned round){
    __syncthreads();
    int tid = threadIdx.x;
    if (blockIdx.x == 0){
        if (tid == 0){
            __threadfence();
            __hip_atomic_store(&flags[0], round, __ATOMIC_RELEASE, __HIP_MEMORY_SCOPE_AGENT);
        }
        unsigned it = 0;
        while (__hip_atomic_load(&flags[tid], __ATOMIC_ACQUIRE, __HIP_MEMORY_SCOPE_AGENT) < round
               && ++it < 4000000u){}
        it = 0;
        while (__hip_atomic_load(&flags[tid + 256], __ATOMIC_ACQUIRE, __HIP_MEMORY_SCOPE_AGENT) < round
               && ++it < 4000000u){}
        __syncthreads();
        if (tid == 0){
            __hip_atomic_store(rel, round, __ATOMIC_RELEASE, __HIP_MEMORY_SCOPE_AGENT);
            __threadfence();
        }
        __syncthreads();
    } else {
        if (tid == 0){
            __threadfence();
            __hip_atomic_store(&flags[blockIdx.x], round, __ATOMIC_RELEASE, __HIP_MEMORY_SCOPE_AGENT);
            unsigned it = 0;
            while (__hip_atomic_load(rel, __ATOMIC_ACQUIRE, __HIP_MEMORY_SCOPE_AGENT) < round
                   && ++it < 4000000u){}
            __threadfence();
        }
        __syncthreads();
    }
}

// ---------------------------------------------------------------------------
// K1: AvgPool3d 16^3 (R7 best: NT loads + in-block LDS reduce).
// Block 0 additionally zeroes the barrier region (stream-ordered before mega).
// ---------------------------------------------------------------------------
__global__ __launch_bounds__(256) void pool_k(const float* __restrict__ x,
                                              float* __restrict__ seq,
                                              unsigned* __restrict__ bar){
    __shared__ float red[4][8];
    int tid  = threadIdx.x;
    int lane = tid & 63;
    int part = tid >> 6;                      // 0..3
    int cdh  = blockIdx.x;                    // 0..4095
    if (cdh == 0){
        for (int i = tid; i < 520; i += 256) bar[i] = 0u;
    }
    int c  = cdh >> 6;
    int od = (cdh >> 3) & 7;
    int oh = cdh & 7;
    int half = lane >> 5;
    int f    = lane & 31;

    const f32x4* px = (const f32x4*)x;
    size_t base = ((size_t)(c * 128 + od * 16) * 128 + (size_t)(oh * 16 + half)) * 32 + f
                + (size_t)part * 4 * 4096;

    float acc = 0.f;
    #pragma unroll
    for (int ii = 0; ii < 4; ii++){
        size_t o = base + (size_t)ii * 4096;
        #pragma unroll
        for (int jj = 0; jj < 8; jj++){
            f32x4 v = __builtin_nontemporal_load(&px[o + (size_t)jj * 64]);
            acc += (v.x + v.y) + (v.z + v.w);
        }
    }
    acc += __shfl_xor(acc, 1);
    acc += __shfl_xor(acc, 2);
    acc += __shfl_xor(acc, 32);
    if (lane < 32 && (lane & 3) == 0) red[part][lane >> 2] = acc;
    __syncthreads();
    if (tid < 8){
        float v = red[0][tid] + red[1][tid] + red[2][tid] + red[3][tid];
        seq[c * 512 + od * 64 + oh * 8 + tid] = v * (1.0f / 4096.0f);
    }
}

// ---------------------------------------------------------------------------
// K2: mega-kernel — all post-pool phases, 3 manual grid barriers.
// 512 blocks x 256 thr, __launch_bounds__(256,2) -> >=2 blocks/CU resident.
// Phase A: in_proj, 8l x 8e per wave (2048 waves)
// Phase B: conv+SiLU+gate + x_proj (256 active blocks, R7 shape)
// Phase C: dt_proj+softplus + parallel scan (2 e's per block)
// Phase D: out_proj, 8l x 8d per wave (512 active waves)
// ---------------------------------------------------------------------------
__global__ __launch_bounds__(256, 2) void mega_k(
        const float* __restrict__ seq,  const float* __restrict__ Win,
        float* __restrict__ xz,
        const float* __restrict__ cw,   const float* __restrict__ cb,
        const float* __restrict__ Wx,
        float* __restrict__ xsT, float* __restrict__ zsT,
        float* __restrict__ bcT, float* __restrict__ xdT,
        const float* __restrict__ Wdt,  const float* __restrict__ bdt,
        const float* __restrict__ A_log,const float* __restrict__ Dv,
        float* __restrict__ y,
        const float* __restrict__ Wo,   float* __restrict__ out,
        unsigned* __restrict__ bar){
    __shared__ float sh[1024];
    unsigned* flags = bar;
    unsigned* rel   = bar + NBLK;
    int tid  = threadIdx.x;
    int lane = tid & 63;
    int bid  = blockIdx.x;
    int wid  = bid * 4 + (tid >> 6);     // 0..2047

    // ---------------- Phase A: in_proj (8l x 8e per wave) ----------------
    {
        int l0 = (wid >> 8) << 3;        // 8 lgroups of 8 rows
        int e0 = (wid & 255) << 3;       // 256 egroups of 8 e
        const f32x4* S = (const f32x4*)seq;
        f32x4 sa[8], sb[8];
        #pragma unroll
        for (int r = 0; r < 8; r++){
            sa[r] = S[(size_t)(l0 + r) * 128 + lane];
            sb[r] = S[(size_t)(l0 + r) * 128 + lane + 64];
        }
        #pragma unroll 2
        for (int j = 0; j < 8; j++){
            int e = e0 + j;
            const f32x4* W = (const f32x4*)Win + (size_t)e * 128;
            f32x4 w0 = W[lane], w1 = W[lane + 64];
            float a[8];
            #pragma unroll
            for (int r = 0; r < 8; r++) a[r] = dot4v(w0, sa[r]) + dot4v(w1, sb[r]);
            float u0 = reduce4(a[0], a[1], a[2], a[3], lane);
            float u1 = reduce4(a[4], a[5], a[6], a[7], lane);
            if (lane < 4){
                xz[(size_t)(l0 + lane) * 2048 + e]     = u0;
                xz[(size_t)(l0 + 4 + lane) * 2048 + e] = u1;
            }
        }
    }
    gbar(flags, rel, 1u);

    // ------- Phase B: conv+SiLU (+gate) + x_proj (256 active blocks) ------
    if (bid < 256){
        int l  = bid >> 2;
        int fg = bid & 3;
        #pragma unroll
        for (int j = 0; j < 4; j++){
            int e = tid + j * 256;
            float v = cb[e];
            #pragma unroll
            for (int tt = 0; tt < 4; tt++){
                int ll = l - 3 + tt;
                if (ll >= 0) v += cw[e * 4 + tt] * xz[(size_t)ll * 2048 + e];
            }
            v = v / (1.f + expf(-v));
            sh[e] = v;
            if (fg == 0){
                xsT[(size_t)e * 64 + l] = v;
                float zv = xz[(size_t)l * 2048 + 1024 + e];
                zsT[(size_t)e * 64 + l] = zv / (1.f + expf(-zv));
            }
        }
        __syncthreads();

        int f = fg * 16 + (tid >> 4);
        int q = tid & 15;
        const float4* X  = (const float4*)sh;
        const float4* W4 = (const float4*)(Wx + (size_t)f * 1024);
        float acc = 0.f;
        #pragma unroll
        for (int k4 = 0; k4 < 16; k4++){
            int idx = q * 16 + k4;
            acc += dot4(X[idx], W4[idx]);
        }
        acc += __shfl_xor(acc, 1);
        acc += __shfl_xor(acc, 2);
        acc += __shfl_xor(acc, 4);
        acc += __shfl_xor(acc, 8);
        if (q == 0){
            if (f < 32) xdT[(size_t)f * 64 + l] = acc;          // dt-rank
            else        bcT[(size_t)(f - 32) * 64 + l] = acc;   // B then C
        }
    }
    gbar(flags, rel, 2u);

    // ---- Phase C: dt_proj+softplus + parallel scan (2 e's per block) ----
    for (int e = bid; e < 1024; e += NBLK){
        __syncthreads();                 // sh reuse guard
        int w = tid >> 6;                // 0..3

        float acc = bdt[e];
        #pragma unroll 8
        for (int k = 0; k < 32; k++) acc += xdT[k * 64 + lane] * Wdt[e * 32 + k];
        float dtv = (acc > 20.f) ? acc : log1pf(expf(acc));
        float xv  = xsT[(size_t)e * 64 + lane];

        float py = 0.f;
        #pragma unroll
        for (int i = 0; i < 4; i++){
            int s = w * 4 + i;
            float A = -expf(A_log[e * 16 + s]);
            float a = expf(dtv * A);
            float b = (dtv * xv) * bcT[s * 64 + lane];
            #pragma unroll
            for (int d = 1; d < 64; d <<= 1){
                float ap = __shfl_up(a, d);
                float bp = __shfl_up(b, d);
                if (lane >= d){ b += a * bp; a *= ap; }
            }
            py += b * bcT[(16 + s) * 64 + lane];
        }
        sh[w * 64 + lane] = py;
        __syncthreads();
        if (tid < 64){
            float tot = sh[lane] + sh[64 + lane] + sh[128 + lane] + sh[192 + lane];
            float yv = (tot + xv * Dv[e]) * zsT[(size_t)e * 64 + lane];
            y[(size_t)lane * 1024 + e] = yv;
        }
    }
    gbar(flags, rel, 3u);

    // ---------------- Phase D: out_proj (8l x 8d, 512 active waves) -------
    if (wid < 512){
        int l0 = (wid >> 6) << 3;        // 8 lgroups of 8 rows
        int d0 = (wid & 63) << 3;        // 64 dgroups of 8 d
        const f32x4* Y = (const f32x4*)y;
        f32x4 yr[8][4];
        #pragma unroll
        for (int r = 0; r < 8; r++){
            #pragma unroll
            for (int q = 0; q < 4; q++)
                yr[r][q] = Y[(size_t)(l0 + r) * 256 + q * 64 + lane];
        }
        #pragma unroll 2
        for (int j = 0; j < 8; j++){
            int d = d0 + j;
            const f32x4* W = (const f32x4*)Wo + (size_t)d * 256;
            float a[8] = {0,0,0,0,0,0,0,0};
            #pragma unroll
            for (int q = 0; q < 4; q++){
                f32x4 w = W[q * 64 + lane];
                #pragma unroll
                for (int r = 0; r < 8; r++) a[r] += dot4v(w, yr[r][q]);
            }
            float u0 = reduce4(a[0], a[1], a[2], a[3], lane);
            float u1 = reduce4(a[4], a[5], a[6], a[7], lane);
            if (lane < 4){
                out[(size_t)(l0 + lane) * 512 + d]     = u0;
                out[(size_t)(l0 + 4 + lane) * 512 + d] = u1;
            }
        }
    }
}

// ---------------------------------------------------------------------------
extern "C" void kernel_launch(void* const* d_in, const int* in_sizes, int n_in,
                              void* d_out, int out_size, void* d_ws, size_t ws_size,
                              hipStream_t stream){
    const float* x          = (const float*)d_in[0];
    const float* in_proj_w  = (const float*)d_in[1];
    const float* conv_w     = (const float*)d_in[2];
    const float* conv_b     = (const float*)d_in[3];
    const float* x_proj_w   = (const float*)d_in[4];
    const float* dt_proj_w  = (const float*)d_in[5];
    const float* dt_proj_b  = (const float*)d_in[6];
    const float* A_log      = (const float*)d_in[7];
    const float* Dv         = (const float*)d_in[8];
    const float* out_proj_w = (const float*)d_in[9];
    float* out = (float*)d_out;

    float* ws   = (float*)d_ws;
    float* seq  = ws;                 // 64*512   = 32768
    float* xz   = ws + 32768;         // 64*2048  = 131072
    float* xsT  = ws + 163840;        // 1024*64  = 65536
    float* zsT  = ws + 229376;        // 1024*64  = 65536
    float* bcT  = ws + 294912;        // 32*64    = 2048
    float* xdT  = ws + 296960;        // 32*64    = 2048
    float* y    = ws + 299008;        // 64*1024  = 65536
    unsigned* bar = (unsigned*)(ws + 364544);  // 520 words

    hipLaunchKernelGGL(pool_k, dim3(4096), dim3(256), 0, stream, x, seq, bar);
    hipLaunchKernelGGL(mega_k, dim3(NBLK), dim3(256), 0, stream,
                       seq, in_proj_w, xz, conv_w, conv_b, x_proj_w,
                       xsT, zsT, bcT, xdT, dt_proj_w, dt_proj_b, A_log, Dv,
                       y, out_proj_w, out, bar);
}

// Round 10
// 123.581 us; speedup vs baseline: 2.6913x; 2.6913x over previous
//
#include <hip/hip_runtime.h>
#include <math.h>

typedef float f32x4 __attribute__((ext_vector_type(4)));

__device__ __forceinline__ float dot4v(f32x4 a, f32x4 b){
    return a.x*b.x + a.y*b.y + a.z*b.z + a.w*b.w;
}
__device__ __forceinline__ float dot4(float4 a, float4 b){
    return a.x*b.x + a.y*b.y + a.z*b.z + a.w*b.w;
}

// Reduce four per-lane values across the 64-lane wave simultaneously.
// Result: lanes with (lane&3)==j hold sum of aj. 7 shuffles total.
__device__ __forceinline__ float reduce4(float a0, float a1, float a2, float a3, int lane){
    int b0 = lane & 1, b1 = lane & 2;
    float r  = b0 ? a1 : a0;
    float rt = b0 ? a0 : a1;
    r += __shfl_xor(rt, 1);
    float s  = b0 ? a3 : a2;
    float st = b0 ? a2 : a3;
    s += __shfl_xor(st, 1);
    float u  = b1 ? s : r;
    float ut = b1 ? r : s;
    u += __shfl_xor(ut, 2);
    u += __shfl_xor(u, 4);
    u += __shfl_xor(u, 8);
    u += __shfl_xor(u, 16);
    u += __shfl_xor(u, 32);
    return u;   // lane&3 selects which sum
}

// ---------------------------------------------------------------------------
// K1: AvgPool3d 16^3 (R7 best: NT loads + in-block LDS reduce).
// Block per (c,od,oh); wave = quarter of the d-window; seq is FINAL.
// ---------------------------------------------------------------------------
__global__ __launch_bounds__(256) void pool_k(const float* __restrict__ x,
                                              float* __restrict__ seq){
    __shared__ float red[4][8];
    int tid  = threadIdx.x;
    int lane = tid & 63;
    int part = tid >> 6;                      // 0..3
    int cdh  = blockIdx.x;                    // 0..4095
    int c  = cdh >> 6;
    int od = (cdh >> 3) & 7;
    int oh = cdh & 7;
    int half = lane >> 5;
    int f    = lane & 31;

    const f32x4* px = (const f32x4*)x;
    size_t base = ((size_t)(c * 128 + od * 16) * 128 + (size_t)(oh * 16 + half)) * 32 + f
                + (size_t)part * 4 * 4096;

    float acc = 0.f;
    #pragma unroll
    for (int ii = 0; ii < 4; ii++){
        size_t o = base + (size_t)ii * 4096;
        #pragma unroll
        for (int jj = 0; jj < 8; jj++){
            f32x4 v = __builtin_nontemporal_load(&px[o + (size_t)jj * 64]);
            acc += (v.x + v.y) + (v.z + v.w);
        }
    }
    acc += __shfl_xor(acc, 1);
    acc += __shfl_xor(acc, 2);
    acc += __shfl_xor(acc, 32);
    if (lane < 32 && (lane & 3) == 0) red[part][lane >> 2] = acc;
    __syncthreads();
    if (tid < 8){
        float v = red[0][tid] + red[1][tid] + red[2][tid] + red[3][tid];
        seq[c * 512 + od * 64 + oh * 8 + tid] = v * (1.0f / 4096.0f);
    }
}

// ---------------------------------------------------------------------------
// K2: in_proj  xz[l,e] = dot(seq[l,:512], Win[e,:512])   (64 x 2048)
// Wave computes 16l x 8e -> only 4 l-groups, so Win is re-read 4x = 16 MB
// (was 32 MB at 8l). 256 blocks x 256 thr = 1024 waves.
// ---------------------------------------------------------------------------
__global__ __launch_bounds__(256) void inproj_k(const float* __restrict__ seq,
                                                const float* __restrict__ Win,
                                                float* __restrict__ xz){
    int lane = threadIdx.x & 63;
    int wid  = blockIdx.x * 4 + (threadIdx.x >> 6);  // 0..1023
    int l0 = (wid >> 8) << 4;        // 4 lgroups of 16 rows
    int e0 = (wid & 255) << 3;       // 256 egroups of 8 e
    const f32x4* S = (const f32x4*)seq;
    f32x4 sa[16], sb[16];
    #pragma unroll
    for (int r = 0; r < 16; r++){
        sa[r] = S[(size_t)(l0 + r) * 128 + lane];
        sb[r] = S[(size_t)(l0 + r) * 128 + lane + 64];
    }
    #pragma unroll 2
    for (int j = 0; j < 8; j++){
        int e = e0 + j;
        const f32x4* W = (const f32x4*)Win + (size_t)e * 128;
        f32x4 w0 = W[lane], w1 = W[lane + 64];
        float a[16];
        #pragma unroll
        for (int r = 0; r < 16; r++) a[r] = dot4v(w0, sa[r]) + dot4v(w1, sb[r]);
        float u0 = reduce4(a[0],  a[1],  a[2],  a[3],  lane);
        float u1 = reduce4(a[4],  a[5],  a[6],  a[7],  lane);
        float u2 = reduce4(a[8],  a[9],  a[10], a[11], lane);
        float u3 = reduce4(a[12], a[13], a[14], a[15], lane);
        if (lane < 4){
            xz[(size_t)(l0 + lane) * 2048 + e]      = u0;
            xz[(size_t)(l0 + 4  + lane) * 2048 + e] = u1;
            xz[(size_t)(l0 + 8  + lane) * 2048 + e] = u2;
            xz[(size_t)(l0 + 12 + lane) * 2048 + e] = u3;
        }
    }
}

// ---------------------------------------------------------------------------
// K3: fused conv1d+SiLU (recomputed per block, trivial FLOPs) + x_proj.
// 256 blocks (l, fgroup) x 256 thr. fgroup==0 blocks also emit xsT/zsT.
// (unchanged R7)
// ---------------------------------------------------------------------------
__global__ __launch_bounds__(256) void xpc_k(const float* __restrict__ xz,
                                             const float* __restrict__ cw,
                                             const float* __restrict__ cb,
                                             const float* __restrict__ Wx,
                                             float* __restrict__ xsT,
                                             float* __restrict__ zsT,
                                             float* __restrict__ bcT,
                                             float* __restrict__ xdT){
    __shared__ float xs_row[1024];
    int bid = blockIdx.x;        // 0..255
    int l  = bid >> 2;
    int fg = bid & 3;
    int t  = threadIdx.x;

    #pragma unroll
    for (int j = 0; j < 4; j++){
        int e = t + j * 256;
        float v = cb[e];
        #pragma unroll
        for (int tt = 0; tt < 4; tt++){
            int ll = l - 3 + tt;
            if (ll >= 0) v += cw[e * 4 + tt] * xz[(size_t)ll * 2048 + e];
        }
        v = v / (1.f + expf(-v));
        xs_row[e] = v;
        if (fg == 0){
            xsT[(size_t)e * 64 + l] = v;
            float zv = xz[(size_t)l * 2048 + 1024 + e];
            zsT[(size_t)e * 64 + l] = zv / (1.f + expf(-zv));
        }
    }
    __syncthreads();

    int f = fg * 16 + (t >> 4);
    int q = t & 15;
    const float4* X  = (const float4*)xs_row;
    const float4* W4 = (const float4*)(Wx + (size_t)f * 1024);
    float acc = 0.f;
    #pragma unroll
    for (int k4 = 0; k4 < 16; k4++){
        int idx = q * 16 + k4;
        acc += dot4(X[idx], W4[idx]);
    }
    acc += __shfl_xor(acc, 1);
    acc += __shfl_xor(acc, 2);
    acc += __shfl_xor(acc, 4);
    acc += __shfl_xor(acc, 8);
    if (q == 0){
        if (f < 32) xdT[(size_t)f * 64 + l] = acc;          // dt-rank part
        else        bcT[(size_t)(f - 32) * 64 + l] = acc;   // B: 0..15, C: 16..31
    }
}

// ---------------------------------------------------------------------------
// K4: fused dt_proj+softplus + parallel selective scan + skip + gate.
// Block per e (1024 blocks x 256 thr). lane = timestep l. (unchanged R5)
// ---------------------------------------------------------------------------
__global__ __launch_bounds__(256) void scan_k(const float* __restrict__ xdT,
                                              const float* __restrict__ bcT,
                                              const float* __restrict__ xsT,
                                              const float* __restrict__ zsT,
                                              const float* __restrict__ Wdt,
                                              const float* __restrict__ bdt,
                                              const float* __restrict__ A_log,
                                              const float* __restrict__ Dv,
                                              float* __restrict__ y){
    __shared__ float red[4][64];
    int e    = blockIdx.x;           // 0..1023
    int lane = threadIdx.x & 63;     // = l
    int w    = threadIdx.x >> 6;     // 0..3

    float acc = bdt[e];
    #pragma unroll 8
    for (int k = 0; k < 32; k++) acc += xdT[k * 64 + lane] * Wdt[e * 32 + k];
    float dtv = (acc > 20.f) ? acc : log1pf(expf(acc));
    float xv  = xsT[(size_t)e * 64 + lane];

    float py = 0.f;
    #pragma unroll
    for (int i = 0; i < 4; i++){
        int s = w * 4 + i;
        float A = -expf(A_log[e * 16 + s]);
        float a = expf(dtv * A);
        float b = (dtv * xv) * bcT[s * 64 + lane];
        #pragma unroll
        for (int d = 1; d < 64; d <<= 1){
            float ap = __shfl_up(a, d);
            float bp = __shfl_up(b, d);
            if (lane >= d){ b += a * bp; a *= ap; }
        }
        py += b * bcT[(16 + s) * 64 + lane];
    }
    red[w][lane] = py;
    __syncthreads();
    if (threadIdx.x < 64){
        float tot = red[0][lane] + red[1][lane] + red[2][lane] + red[3][lane];
        float yv = (tot + xv * Dv[e]) * zsT[(size_t)e * 64 + lane];
        y[(size_t)lane * 1024 + e] = yv;
    }
}

// ---------------------------------------------------------------------------
// K5: out_proj  out[l,d] = dot(y[l,:1024], Wo[d,:1024])  (64 x 512)
// Wave computes 8l x 8d -> 8 l-groups, Wo re-read 8x = 16 MB (was 32 MB).
// 128 blocks x 256 thr = 512 waves.
// ---------------------------------------------------------------------------
__global__ __launch_bounds__(256) void outproj_k(const float* __restrict__ y,
                                                 const float* __restrict__ Wo,
                                                 float* __restrict__ out){
    int lane = threadIdx.x & 63;
    int wid  = blockIdx.x * 4 + (threadIdx.x >> 6);  // 0..511
    int l0 = (wid >> 6) << 3;        // 8 lgroups of 8 rows
    int d0 = (wid & 63) << 3;        // 64 dgroups of 8 d
    const f32x4* Y = (const f32x4*)y;
    f32x4 yr[8][4];
    #pragma unroll
    for (int r = 0; r < 8; r++){
        #pragma unroll
        for (int q = 0; q < 4; q++)
            yr[r][q] = Y[(size_t)(l0 + r) * 256 + q * 64 + lane];
    }
    #pragma unroll 2
    for (int j = 0; j < 8; j++){
        int d = d0 + j;
        const f32x4* W = (const f32x4*)Wo + (size_t)d * 256;
        float a[8] = {0,0,0,0,0,0,0,0};
        #pragma unroll
        for (int q = 0; q < 4; q++){
            f32x4 w = W[q * 64 + lane];
            #pragma unroll
            for (int r = 0; r < 8; r++) a[r] += dot4v(w, yr[r][q]);
        }
        float u0 = reduce4(a[0], a[1], a[2], a[3], lane);
        float u1 = reduce4(a[4], a[5], a[6], a[7], lane);
        if (lane < 4){
            out[(size_t)(l0 + lane) * 512 + d]     = u0;
            out[(size_t)(l0 + 4 + lane) * 512 + d] = u1;
        }
    }
}

// ---------------------------------------------------------------------------
extern "C" void kernel_launch(void* const* d_in, const int* in_sizes, int n_in,
                              void* d_out, int out_size, void* d_ws, size_t ws_size,
                              hipStream_t stream){
    const float* x          = (const float*)d_in[0];
    const float* in_proj_w  = (const float*)d_in[1];
    const float* conv_w     = (const float*)d_in[2];
    const float* conv_b     = (const float*)d_in[3];
    const float* x_proj_w   = (const float*)d_in[4];
    const float* dt_proj_w  = (const float*)d_in[5];
    const float* dt_proj_b  = (const float*)d_in[6];
    const float* A_log      = (const float*)d_in[7];
    const float* Dv         = (const float*)d_in[8];
    const float* out_proj_w = (const float*)d_in[9];
    float* out = (float*)d_out;

    float* ws   = (float*)d_ws;
    float* seq  = ws;            // 64*512   = 32768
    float* xz   = ws + 32768;    // 64*2048  = 131072
    float* xsT  = ws + 163840;   // 1024*64  = 65536
    float* zsT  = ws + 229376;   // 1024*64  = 65536
    float* bcT  = ws + 294912;   // 32*64    = 2048
    float* xdT  = ws + 296960;   // 32*64    = 2048
    float* y    = ws + 299008;   // 64*1024  = 65536

    hipLaunchKernelGGL(pool_k,    dim3(4096), dim3(256), 0, stream, x, seq);
    hipLaunchKernelGGL(inproj_k,  dim3(256),  dim3(256), 0, stream, seq, in_proj_w, xz);
    hipLaunchKernelGGL(xpc_k,     dim3(256),  dim3(256), 0, stream, xz, conv_w, conv_b,
                       x_proj_w, xsT, zsT, bcT, xdT);
    hipLaunchKernelGGL(scan_k,    dim3(1024), dim3(256), 0, stream, xdT, bcT, xsT, zsT,
                       dt_proj_w, dt_proj_b, A_log, Dv, y);
    hipLaunchKernelGGL(outproj_k, dim3(128),  dim3(256), 0, stream, y, out_proj_w, out);
}